// Round 7
// baseline (271.701 us; speedup 1.0000x reference)
//
#include <hip/hip_runtime.h>
#include <hip/hip_bf16.h>

typedef __attribute__((ext_vector_type(8))) short short8;
typedef __attribute__((ext_vector_type(4))) float floatx4;

#define N_ROWS 32768
#define D_DIM  128
#define H_KEYS 8192
#define C_COLS 100
#define BM     128      // rows per block (32 per wave)
#define OL_STRIDE 113   // floats per OL row (odd -> conflict-free epilogue)
#define LOG2E 1.4426950408889634f

// NOTE (hard-won): __launch_bounds__(256, w) caps ARCH VGPRs at 256/w; w>=3
// spilled (GBs of scratch). CSV VGPR_Count excludes AGPRs: R6 measured
// 108 arch + ~64 acc -> 2 waves/SIMD residency. This version needs ~200
// total -> 2 waves/SIMD anyway, so no waves arg: never cap below need.

__device__ __forceinline__ unsigned short f2bf(float f) {
  union { float f; unsigned int u; } v; v.f = f;
  unsigned int r = v.u + 0x7fffu + ((v.u >> 16) & 1u);  // RNE
  return (unsigned short)(r >> 16);
}

// v_cvt_pk_bf16_f32: two fp32 -> packed bf16
__device__ __forceinline__ unsigned int pk2bf(float a, float b) {
  union { __hip_bfloat162 h; unsigned int u; } c;
  c.h = __float22bfloat162_rn(float2{a, b});
  return c.u;
}

// ---- merged prep: blocks [0,512) pack K (scaled) + ksq; [512,768) pack V ----
__global__ void prep_kernel(const float* __restrict__ keys,
                            const float* __restrict__ values,
                            const float* __restrict__ temp,
                            unsigned short* __restrict__ kp,
                            float* __restrict__ ksq,
                            unsigned short* __restrict__ vp) {
  int tid = threadIdx.x;
  if (blockIdx.x < 512) {
    // K pack (physical order): block rt covers key rows [16rt, 16rt+16).
    __shared__ float red[256];
    int rt = blockIdx.x;
    int lane = tid & 63;
    int c = tid >> 6;
    float scale = 2.0f * LOG2E / temp[0];
    int row = rt * 16 + (lane & 15);
    int d0 = c * 32 + (lane >> 4) * 8;
    const float* s = keys + (size_t)row * D_DIM + d0;
    float4 lo = *(const float4*)s;
    float4 hi = *(const float4*)(s + 4);
    float sq = lo.x*lo.x + lo.y*lo.y + lo.z*lo.z + lo.w*lo.w
             + hi.x*hi.x + hi.y*hi.y + hi.z*hi.z + hi.w*hi.w;
    red[c * 64 + lane] = sq;
    union { short8 v; unsigned int u[4]; } cv;
    cv.u[0] = pk2bf(lo.x * scale, lo.y * scale);
    cv.u[1] = pk2bf(lo.z * scale, lo.w * scale);
    cv.u[2] = pk2bf(hi.x * scale, hi.y * scale);
    cv.u[3] = pk2bf(hi.z * scale, hi.w * scale);
    *(short8*)(kp + ((size_t)(rt * 4 + c) * 64 + lane) * 8) = cv.v;
    __syncthreads();
    if (tid < 16) {
      float acc = 0.f;
#pragma unroll
      for (int cc = 0; cc < 4; ++cc)
#pragma unroll
        for (int qq = 0; qq < 4; ++qq)
          acc += red[cc * 64 + qq * 16 + tid];
      ksq[rt * 16 + tid] = -acc * LOG2E / temp[0];
    }
  } else {
    // V pack, PERMUTED within each 32-key group so the S-MFMA C/D output
    // (after exp2+pack) is directly the PV A-fragment:
    // B-slot k = q*8+j  <-  physical key  phi = (j>>2)*16 + q*4 + (j&3).
    // Pad to 112 cols; ones-column at col 100 = softmax denominator.
    __shared__ float vt[32 * 113];
    int g = blockIdx.x - 512;           // 32-key group
    for (int idx = tid; idx < 32 * 112; idx += 256) {
      int k = idx / 112, col = idx - k * 112;
      float val;
      if (col < C_COLS) val = values[(size_t)(g * 32 + k) * C_COLS + col];
      else val = (col == C_COLS) ? 1.0f : 0.0f;
      vt[k * 113 + col] = val;
    }
    __syncthreads();
    for (int u = tid; u < 7 * 64; u += 256) {
      int ct = u >> 6, l = u & 63;
      int n0 = l & 15, q = l >> 4;
      short8 o;
#pragma unroll
      for (int j = 0; j < 8; ++j) {
        int src = ((j >> 2) << 4) + q * 4 + (j & 3);   // phi(k)
        o[j] = (short)f2bf(vt[src * 113 + ct * 16 + n0]);
      }
      *(short8*)(vp + ((size_t)(g * 7 + ct) * 64 + l) * 8) = o;
    }
  }
}

// Fused RBF attention, register-resident P (no LDS, no barriers in loop).
// Waves split xrows (32 each of BM=128); every wave processes all keys of
// its half. Grid 512 = 256 row-blocks x 2 key halves = one resident round.
__global__ __launch_bounds__(256)
void attn_rbf_kernel(const float* __restrict__ x,
                     const unsigned short* __restrict__ kp,
                     const float* __restrict__ ksq,
                     const unsigned short* __restrict__ vp,
                     float* __restrict__ outA, float* __restrict__ denA,
                     float* __restrict__ outB, float* __restrict__ denB) {
  __shared__ __align__(16) float OL[BM * OL_STRIDE];  // 57,856 B, epilogue only

  const int tid = threadIdx.x;
  const int w = tid >> 6;       // wave 0..3 -> rows [32w, 32w+32)
  const int lane = tid & 63;
  const int n0 = lane & 15;
  const int q = lane >> 4;
  const int b = blockIdx.x >> 1;
  const int kb = blockIdx.x & 1;

  // x rows for this wave (fp32 row-major) -> bf16 B-fragments in registers.
  short8 xf[2][4];
#pragma unroll
  for (int rt = 0; rt < 2; ++rt)
#pragma unroll
    for (int c = 0; c < 4; ++c) {
      const float* s = x + (size_t)(b * BM + w * 32 + rt * 16 + n0) * D_DIM + c * 32 + q * 8;
      float4 lo = *(const float4*)s;
      float4 hi = *(const float4*)(s + 4);
      union { short8 v; unsigned int u[4]; } cv;
      cv.u[0] = pk2bf(lo.x, lo.y);
      cv.u[1] = pk2bf(lo.z, lo.w);
      cv.u[2] = pk2bf(hi.x, hi.y);
      cv.u[3] = pk2bf(hi.z, hi.w);
      xf[rt][c] = cv.v;
    }

  floatx4 oacc[2][7];
#pragma unroll
  for (int rt = 0; rt < 2; ++rt)
#pragma unroll
    for (int ct = 0; ct < 7; ++ct)
      oacc[rt][ct] = (floatx4){0.f, 0.f, 0.f, 0.f};

  for (int it = 0; it < 128; ++it) {
    const int g = kb * 128 + it;          // global 32-key group

    // ---- global loads (L1/L2-resident; shared across the 4 waves) ----
    short8 kf[2][4];
#pragma unroll
    for (int kt = 0; kt < 2; ++kt)
#pragma unroll
      for (int c = 0; c < 4; ++c)
        kf[kt][c] = *(const short8*)(kp + ((size_t)((g * 2 + kt) * 4 + c) * 64 + lane) * 8);

    short8 vf[7];
#pragma unroll
    for (int ct = 0; ct < 7; ++ct)
      vf[ct] = *(const short8*)(vp + ((size_t)(g * 7 + ct) * 64 + lane) * 8);

    floatx4 ksq4[2];
#pragma unroll
    for (int kt = 0; kt < 2; ++kt)
      ksq4[kt] = *(const floatx4*)(ksq + g * 32 + kt * 16 + q * 4);

    // ---- S^T = K . X^T, C-init = -ksq*log2e/T (folded bias) ----
    floatx4 s[2][2];
#pragma unroll
    for (int kt = 0; kt < 2; ++kt)
#pragma unroll
      for (int rt = 0; rt < 2; ++rt)
        s[kt][rt] = ksq4[kt];
#pragma unroll
    for (int c = 0; c < 4; ++c)
#pragma unroll
      for (int kt = 0; kt < 2; ++kt)
#pragma unroll
        for (int rt = 0; rt < 2; ++rt)
          s[kt][rt] = __builtin_amdgcn_mfma_f32_16x16x32_bf16(kf[kt][c], xf[rt][c], s[kt][rt], 0, 0, 0);

    // ---- P = exp2(S), packed in-register into the PV A-fragment ----
    short8 pf[2];
#pragma unroll
    for (int rt = 0; rt < 2; ++rt) {
      union { short8 v; unsigned int u[4]; } pu;
      pu.u[0] = pk2bf(__builtin_amdgcn_exp2f(s[0][rt][0]), __builtin_amdgcn_exp2f(s[0][rt][1]));
      pu.u[1] = pk2bf(__builtin_amdgcn_exp2f(s[0][rt][2]), __builtin_amdgcn_exp2f(s[0][rt][3]));
      pu.u[2] = pk2bf(__builtin_amdgcn_exp2f(s[1][rt][0]), __builtin_amdgcn_exp2f(s[1][rt][1]));
      pu.u[3] = pk2bf(__builtin_amdgcn_exp2f(s[1][rt][2]), __builtin_amdgcn_exp2f(s[1][rt][3]));
      pf[rt] = pu.v;
    }

    // ---- O += P . V (V rows pre-permuted to match pf's key order) ----
#pragma unroll
    for (int ct = 0; ct < 7; ++ct)
#pragma unroll
      for (int rt = 0; rt < 2; ++rt)
        oacc[rt][ct] = __builtin_amdgcn_mfma_f32_16x16x32_bf16(pf[rt], vf[ct], oacc[rt][ct], 0, 0, 0);
  }

  // ---- epilogue: stage fp32 tile in LDS, write unnormalized partial ----
  // PV C/D: lane(n0,q) reg i -> row = q*4+i (xrow within rt tile), col = n0.
#pragma unroll
  for (int rt = 0; rt < 2; ++rt)
#pragma unroll
    for (int ct = 0; ct < 7; ++ct)
#pragma unroll
      for (int i = 0; i < 4; ++i)
        OL[(w * 32 + rt * 16 + q * 4 + i) * OL_STRIDE + ct * 16 + n0] = oacc[rt][ct][i];
  __syncthreads();

  float* dst  = kb ? outB : outA;
  float* dden = kb ? denB : denA;
  float* dstb = dst + (size_t)b * (BM * C_COLS);
  for (int idx = tid; idx < BM * C_COLS; idx += 256) {
    int n = idx / C_COLS;
    int cc = idx - n * C_COLS;
    dstb[idx] = OL[n * OL_STRIDE + cc];
  }
  if (tid < BM) dden[b * BM + tid] = OL[tid * OL_STRIDE + 100];
}

// out = (outA + outB) / (denA + denB), float4 over 25 vec4 per 100-col row
__global__ void combine_kernel(float* __restrict__ outA,
                               const float* __restrict__ outB,
                               const float* __restrict__ denA,
                               const float* __restrict__ denB) {
  int v = blockIdx.x * 256 + threadIdx.x;     // float4 index
  int n = v / 25;                             // row
  float4 a  = *(const float4*)(outA + (size_t)v * 4);
  float4 bb = *(const float4*)(outB + (size_t)v * 4);
  float r = 1.0f / (denA[n] + denB[n]);
  float4 o;
  o.x = (a.x + bb.x) * r; o.y = (a.y + bb.y) * r;
  o.z = (a.z + bb.z) * r; o.w = (a.w + bb.w) * r;
  *(float4*)(outA + (size_t)v * 4) = o;
}

extern "C" void kernel_launch(void* const* d_in, const int* in_sizes, int n_in,
                              void* d_out, int out_size, void* d_ws, size_t ws_size,
                              hipStream_t stream) {
  (void)in_sizes; (void)n_in; (void)out_size; (void)ws_size;
  const float* x      = (const float*)d_in[0];
  const float* keys   = (const float*)d_in[1];
  const float* values = (const float*)d_in[2];
  const float* temp   = (const float*)d_in[3];
  float* out = (float*)d_out;

  char* ws = (char*)d_ws;
  unsigned short* kp  = (unsigned short*)(ws);              //  2,097,152 B
  unsigned short* vp  = (unsigned short*)(ws + 2097152);    //  1,835,008 B
  float*          ksq = (float*)(ws + 3932160);             //     32,768 B
  float*          denA= (float*)(ws + 3964928);             //    131,072 B
  float*          denB= (float*)(ws + 4096000);             //    131,072 B
  float*          outB= (float*)(ws + 4227072);             // 13,107,200 B (tot ~17.3 MB)

  hipLaunchKernelGGL(prep_kernel,     dim3(768),  dim3(256), 0, stream,
                     keys, values, temp, kp, ksq, vp);
  hipLaunchKernelGGL(attn_rbf_kernel, dim3(512),  dim3(256), 0, stream,
                     x, kp, ksq, vp, out, denA, outB, denB);
  hipLaunchKernelGGL(combine_kernel,  dim3(3200), dim3(256), 0, stream,
                     out, outB, denA, denB);
}